// Round 1
// baseline (2047.714 us; speedup 1.0000x reference)
//
#include <hip/hip_runtime.h>

// LSTM_Seq2Dis: emb -> LSTM(rec-dropout) -> maxpool2 -> [relu FC + drop] x2 -> sigmoid FC
// B=64 T=128 H=50 V=8192.  Heavy part: two 4096x8192x8192 GEMMs -> bf16 MFMA.

#define Bc 64
#define Tc 128
#define Hc 50
#define Vc 8192
#define Mrows 4096   // B * T/2

typedef unsigned short u16;
typedef short bf16x8 __attribute__((ext_vector_type(8)));
typedef float f32x4 __attribute__((ext_vector_type(4)));

__device__ __forceinline__ u16 f2bf(float x) {
  union { float f; unsigned int u; } v; v.f = x;
  unsigned int r = v.u + 0x7fffu + ((v.u >> 16) & 1u);   // RNE
  return (u16)(r >> 16);
}

__device__ __forceinline__ void async_copy16(void* lds, const void* g) {
  __builtin_amdgcn_global_load_lds(
      (const __attribute__((address_space(1))) void*)g,
      (__attribute__((address_space(3))) void*)lds, 16, 0, 0);
}

__device__ __forceinline__ float sigmoidf(float x) {
  return 1.0f / (1.0f + __expf(-x));
}

// ---------------------------------------------------------------------------
// zx[t][b][j] = b[j] + sum_h E[tok[b][t]][h] * Wx[h][j]     (j in [0,200))
// one block per (t,b) token
__global__ __launch_bounds__(256) void zx_kernel(
    const int* __restrict__ tok, const float* __restrict__ E,
    const float* __restrict__ Wx, const float* __restrict__ bvec,
    float* __restrict__ zx) {
  const int tb = blockIdx.x;              // tb = t*64 + b
  const int t = tb >> 6, b = tb & 63;
  __shared__ float e_s[Hc];
  const int id = tok[b * Tc + t];
  if (threadIdx.x < Hc) e_s[threadIdx.x] = E[id * Hc + threadIdx.x];
  __syncthreads();
  if (threadIdx.x < 4 * Hc) {
    float acc = bvec[threadIdx.x];
    #pragma unroll
    for (int h = 0; h < Hc; ++h) acc += e_s[h] * Wx[h * 200 + threadIdx.x];
    zx[(size_t)tb * 200 + threadIdx.x] = acc;
  }
}

// ---------------------------------------------------------------------------
// LSTM scan, one block per batch element b. Fused MaxPool1D(2) -> bf16 pooled
// pooled[(b*64 + p)*64 + k], k in [0,64): cols 50..63 zero-padded.
__global__ __launch_bounds__(256) void lstm_kernel(
    const float* __restrict__ zx, const float* __restrict__ U,
    const float* __restrict__ rec_mask, u16* __restrict__ pooled) {
  const int b = blockIdx.x;
  const int tid = threadIdx.x;
  __shared__ float Us[4 * Hc * Hc];    // 40 KB
  __shared__ float recm[4 * Hc];
  __shared__ float h_s[Hc], c_s[Hc], hprev[Hc];
  __shared__ float hm[4 * Hc], z_s[4 * Hc];

  for (int i = tid; i < 4 * Hc * Hc; i += 256) Us[i] = U[i];
  if (tid < 200) recm[tid] = rec_mask[(tid / Hc) * Bc * Hc + b * Hc + (tid % Hc)];
  if (tid < Hc) { h_s[tid] = 0.f; c_s[tid] = 0.f; }
  __syncthreads();

  for (int t = 0; t < Tc; ++t) {
    if (tid < 200) hm[tid] = h_s[tid % Hc] * recm[tid];
    __syncthreads();
    if (tid < 200) {
      const int g = tid / Hc, k = tid % Hc;
      float acc = zx[((size_t)t * Bc + b) * 200 + tid];
      const float* Ug = Us + g * Hc * Hc;
      const float* hmg = hm + g * Hc;
      #pragma unroll
      for (int h = 0; h < Hc; ++h) acc += hmg[h] * Ug[h * Hc + k];
      z_s[tid] = acc;
    }
    __syncthreads();
    if (tid < Hc) {
      const int k = tid;
      const float i_ = sigmoidf(z_s[k]);
      const float f_ = sigmoidf(z_s[Hc + k]);
      const float g_ = tanhf(z_s[2 * Hc + k]);
      const float o_ = sigmoidf(z_s[3 * Hc + k]);
      const float c = f_ * c_s[k] + i_ * g_;
      const float h = o_ * tanhf(c);
      c_s[k] = c; h_s[k] = h;
      if ((t & 1) != 0) {
        pooled[((size_t)b * 64 + (t >> 1)) * 64 + k] = f2bf(fmaxf(hprev[k], h));
      } else {
        hprev[k] = h;
      }
    }
    if ((t & 1) != 0 && tid >= Hc && tid < 64)
      pooled[((size_t)b * 64 + (t >> 1)) * 64 + tid] = 0;   // K-pad
    __syncthreads();
  }
}

// ---------------------------------------------------------------------------
// W1 [50][8192] f32 -> W1T [8192][64] bf16 (transpose, K zero-padded to 64)
__global__ __launch_bounds__(256) void w1t_kernel(
    const float* __restrict__ W1, u16* __restrict__ W1T) {
  const int idx = blockIdx.x * 256 + threadIdx.x;   // idx = n*64 + k
  const int n = idx >> 6, k = idx & 63;
  const float v = (k < Hc) ? W1[(size_t)k * Vc + n] : 0.f;
  W1T[idx] = f2bf(v);
}

// ---------------------------------------------------------------------------
// W [8192][8192] f32 -> WT [8192][8192] bf16 transposed ([n][k]).
// 128(k) x 64(n) tile through LDS; coalesced read + ushort2 coalesced write.
__global__ __launch_bounds__(256) void wt_kernel(
    const float* __restrict__ W, u16* __restrict__ WT) {
  __shared__ float sm[128][65];
  const int t = threadIdx.x;
  const size_t k0 = (size_t)blockIdx.x * 128;
  const size_t n0 = (size_t)blockIdx.y * 64;
  {
    const int n = t & 63, kr = t >> 6;
    #pragma unroll
    for (int i = 0; i < 32; ++i) {
      const int k = i * 4 + kr;
      sm[k][n] = W[(k0 + k) * Vc + n0 + n];
    }
  }
  __syncthreads();
  {
    const int kk = (t & 63) * 2, nr = t >> 6;
    #pragma unroll
    for (int i = 0; i < 16; ++i) {
      const int nn = i * 4 + nr;
      ushort2 v;
      v.x = f2bf(sm[kk][nn]);
      v.y = f2bf(sm[kk + 1][nn]);
      *(ushort2*)&WT[(n0 + nn) * Vc + k0 + kk] = v;
    }
  }
}

// ---------------------------------------------------------------------------
// C[M][N] = epilogue(A[M][K] @ Bt[N][K]^T + bias)
//   SIGMOID=false: relu(z) * mask -> bf16 store
//   SIGMOID=true : sigmoid(z)     -> f32 store
// 128x128 tile, BK=64, 4 waves x (4x4) mfma_f32_16x16x32_bf16.
// global_load_lds(16B) staging; XOR-swizzled LDS chunks (slot = chunk ^ (row&7))
// so ds_read_b128 fragment loads are conflict-free.
template <bool SIGMOID>
__global__ __launch_bounds__(256, 2) void gemm_bt(
    const u16* __restrict__ A, const u16* __restrict__ Bt,
    const float* __restrict__ bias, const float* __restrict__ mask,
    void* __restrict__ Cout, const int M, const int N, const int K) {
  __shared__ u16 As[128 * 64];
  __shared__ u16 Bs[128 * 64];
  const int tid = threadIdx.x;
  const int wave = tid >> 6;
  const int lane = tid & 63;
  const int wr = (wave >> 1) << 6;    // 0 / 64
  const int wc = (wave & 1) << 6;     // 0 / 64
  const long tileM = (long)blockIdx.y * 128;
  const long tileN = (long)blockIdx.x * 128;

  // staging geometry: issue q = wave*4+q4 covers rows q*8..q*8+7 (row=128B)
  const int lrow = lane >> 3;                       // 0..7
  const int cg8 = (((lane & 7) ^ lrow) << 3);       // swizzled k-elem offset
  const u16* Ab = A + tileM * K;
  const u16* Bb = Bt + tileN * K;

  f32x4 acc[4][4] = {};

  for (int k0 = 0; k0 < K; k0 += 64) {
    #pragma unroll
    for (int q4 = 0; q4 < 4; ++q4) {
      const int r = (wave << 5) + (q4 << 3) + lrow;
      const int ldsoff = (wave * 4 + q4) << 10;     // bytes
      async_copy16((char*)As + ldsoff, Ab + (long)r * K + k0 + cg8);
      async_copy16((char*)Bs + ldsoff, Bb + (long)r * K + k0 + cg8);
    }
    __syncthreads();
    #pragma unroll
    for (int kk = 0; kk < 64; kk += 32) {
      const int ch = (kk >> 3) + (lane >> 4);       // chunk 0..7
      bf16x8 af[4], bf[4];
      #pragma unroll
      for (int i = 0; i < 4; ++i) {
        const int ra = wr + (i << 4) + (lane & 15);
        af[i] = *(const bf16x8*)(As + ra * 64 + ((ch ^ (ra & 7)) << 3));
      }
      #pragma unroll
      for (int j = 0; j < 4; ++j) {
        const int rb = wc + (j << 4) + (lane & 15);
        bf[j] = *(const bf16x8*)(Bs + rb * 64 + ((ch ^ (rb & 7)) << 3));
      }
      #pragma unroll
      for (int i = 0; i < 4; ++i)
        #pragma unroll
        for (int j = 0; j < 4; ++j)
          acc[i][j] = __builtin_amdgcn_mfma_f32_16x16x32_bf16(af[i], bf[j], acc[i][j], 0, 0, 0);
    }
    __syncthreads();
  }

  // epilogue: C/D layout col=lane&15, row=(lane>>4)*4+reg
  const int qrow = (lane >> 4) << 2;
  const int qcol = lane & 15;
  #pragma unroll
  for (int j = 0; j < 4; ++j) {
    const long col = tileN + wc + (j << 4) + qcol;
    const float bv = bias[col];
    #pragma unroll
    for (int i = 0; i < 4; ++i) {
      const long row0 = tileM + wr + (i << 4) + qrow;
      #pragma unroll
      for (int r = 0; r < 4; ++r) {
        const long off = (row0 + r) * N + col;
        const float z = acc[i][j][r] + bv;
        if constexpr (SIGMOID) {
          ((float*)Cout)[off] = sigmoidf(z);
        } else {
          ((u16*)Cout)[off] = f2bf(fmaxf(z, 0.f) * mask[off]);
        }
      }
    }
  }
}

// ---------------------------------------------------------------------------
extern "C" void kernel_launch(void* const* d_in, const int* in_sizes, int n_in,
                              void* d_out, int out_size, void* d_ws, size_t ws_size,
                              hipStream_t stream) {
  const int*   tok  = (const int*)  d_in[0];
  const float* E    = (const float*)d_in[1];
  const float* Wx   = (const float*)d_in[2];
  const float* U    = (const float*)d_in[3];
  const float* bvec = (const float*)d_in[4];
  const float* W1   = (const float*)d_in[5];
  const float* b1   = (const float*)d_in[6];
  const float* W1b  = (const float*)d_in[7];
  const float* W2   = (const float*)d_in[8];
  const float* b2   = (const float*)d_in[9];
  const float* recm = (const float*)d_in[10];
  const float* dm1  = (const float*)d_in[11];
  const float* dm2  = (const float*)d_in[12];
  float* out = (float*)d_out;

  char* w = (char*)d_ws;
  u16* Wt     = (u16*)w;  w += (size_t)Vc * Vc * 2;        // 128 MB (reused W1b/W2)
  u16* A1     = (u16*)w;  w += (size_t)Mrows * Vc * 2;     // 64 MB
  u16* A2     = (u16*)w;  w += (size_t)Mrows * Vc * 2;     // 64 MB
  u16* W1T    = (u16*)w;  w += (size_t)Vc * 64 * 2;        // 1 MB
  u16* pooled = (u16*)w;  w += (size_t)Mrows * 64 * 2;     // 0.5 MB
  float* zx   = (float*)w;                                  // 6.25 MB

  zx_kernel  <<<Bc * Tc, 256, 0, stream>>>(tok, E, Wx, bvec, zx);
  lstm_kernel<<<Bc, 256, 0, stream>>>(zx, U, recm, pooled);
  w1t_kernel <<<(Vc * 64) / 256, 256, 0, stream>>>(W1, W1T);
  // d1 = relu(pooled @ W1 + b1) * dmask1  -> A1 (bf16)
  gemm_bt<false><<<dim3(Vc / 128, Mrows / 128), 256, 0, stream>>>(
      pooled, W1T, b1, dm1, A1, Mrows, Vc, 64);
  // d2 = relu(A1 @ W1b + b1) * dmask2 -> A2 (bf16)
  wt_kernel<<<dim3(Vc / 128, Vc / 64), 256, 0, stream>>>(W1b, Wt);
  gemm_bt<false><<<dim3(Vc / 128, Mrows / 128), 256, 0, stream>>>(
      A1, Wt, b1, dm2, A2, Mrows, Vc, Vc);
  // prbs = sigmoid(A2 @ W2 + b2) -> out (f32)
  wt_kernel<<<dim3(Vc / 128, Vc / 64), 256, 0, stream>>>(W2, Wt);
  gemm_bt<true><<<dim3(Vc / 128, Mrows / 128), 256, 0, stream>>>(
      A2, Wt, b2, nullptr, out, Mrows, Vc, Vc);
}